// Round 2
// baseline (916.320 us; speedup 1.0000x reference)
//
#include <hip/hip_runtime.h>
#include <hip/hip_bf16.h>
#include <cstdint>

#define T_DIM 2048
#define B_DIM 16
#define D_DIM 1024
#define N3    (3*D_DIM)          // 3072
#define M_ROWS (T_DIM*B_DIM)     // 32768
#define HALF  (D_DIM/2)          // 512
#define SEG    32
#define SEGLEN (T_DIM/SEG)       // 64
#define NSEQ  (2*B_DIM*HALF)     // 16384

typedef __attribute__((ext_vector_type(8))) short bf16x8;
typedef __attribute__((ext_vector_type(4))) float f32x4;

#define GLD_LDS16(g, l) __builtin_amdgcn_global_load_lds( \
    (const __attribute__((address_space(1))) void*)(g),   \
    (__attribute__((address_space(3))) void*)(l), 16, 0, 0)

__device__ __forceinline__ ushort f2bf(float x) {
    __hip_bfloat16 h = __float2bfloat16(x);
    return *reinterpret_cast<ushort*>(&h);
}

__device__ __forceinline__ float sigmoidf(float x) {
    return 1.0f / (1.0f + __expf(-x));
}

// ---------------- cast input (fp32 -> bf16), 8 elems/thread ----------------
__global__ __launch_bounds__(256) void cast_a(const float* __restrict__ in,
                                              ushort* __restrict__ out) {
    const size_t i = (size_t)blockIdx.x * 256 + threadIdx.x; // handles 8 elems
    const float4* p = (const float4*)in + i * 2;
    float4 a = p[0], b = p[1];
    float f[8] = {a.x, a.y, a.z, a.w, b.x, b.y, b.z, b.w};
    ushort r[8];
#pragma unroll
    for (int j = 0; j < 8; ++j) r[j] = f2bf(f[j]);
    *(uint4*)(out + i * 8) = *(const uint4*)r;
}

// ---------------- W (1024 x 3072) -> W^T (3072 x 1024) bf16 ----------------
__global__ __launch_bounds__(256) void transpose_cast(const float* __restrict__ W,
                                                      ushort* __restrict__ WT) {
    __shared__ float tile[64][65];
    const int c0 = blockIdx.x * 64;  // N dim of W
    const int r0 = blockIdx.y * 64;  // K dim of W
    const int tr = threadIdx.x >> 6; // 0..3
    const int tc = threadIdx.x & 63;
#pragma unroll
    for (int i = 0; i < 16; ++i) {
        const int r = tr + i * 4;
        tile[r][tc] = W[(size_t)(r0 + r) * N3 + c0 + tc];
    }
    __syncthreads();
#pragma unroll
    for (int i = 0; i < 16; ++i) {
        const int r = tr + i * 4;  // row of WT = col of W
        WT[(size_t)(c0 + r) * D_DIM + r0 + tc] = f2bf(tile[tc][r]);
    }
}

// ---------------- GEMM: C(32768x3072) = A(32768x1024) * B, BT is N x K -----
__global__ __launch_bounds__(256) void gemm_bf16(const ushort* __restrict__ A,
                                                 const ushort* __restrict__ BT,
                                                 float* __restrict__ C) {
    const int K = D_DIM;
    const int N = N3;
    __shared__ ushort As[128 * 64];
    __shared__ ushort Bs[128 * 64];
    const int tid  = threadIdx.x;
    const int wave = tid >> 6;
    const int lane = tid & 63;
    const int m0 = blockIdx.x * 128;
    const int n0 = blockIdx.y * 128;
    const int wm = wave >> 1;
    const int wn = wave & 1;

    f32x4 acc[4][4] = {};

    const int srow = lane >> 3;        // row within 8-row staging group
    const int skc  = (lane & 7) * 8;   // k-element offset within row

    for (int k0 = 0; k0 < K; k0 += 64) {
#pragma unroll
        for (int it = 0; it < 4; ++it) {
            const int rb = it * 32 + wave * 8;
            GLD_LDS16(A  + (size_t)(m0 + rb + srow) * K + k0 + skc, &As[rb * 64]);
            GLD_LDS16(BT + (size_t)(n0 + rb + srow) * K + k0 + skc, &Bs[rb * 64]);
        }
        __syncthreads();
        const int q  = lane >> 4;
        const int lm = lane & 15;
#pragma unroll
        for (int kk = 0; kk < 2; ++kk) {
            bf16x8 af[4], bfr[4];
#pragma unroll
            for (int i = 0; i < 4; ++i) {
                af[i]  = *(const bf16x8*)&As[(wm * 64 + i * 16 + lm) * 64 + kk * 32 + q * 8];
                bfr[i] = *(const bf16x8*)&Bs[(wn * 64 + i * 16 + lm) * 64 + kk * 32 + q * 8];
            }
#pragma unroll
            for (int i = 0; i < 4; ++i)
#pragma unroll
                for (int j = 0; j < 4; ++j)
                    acc[i][j] = __builtin_amdgcn_mfma_f32_16x16x32_bf16(af[i], bfr[j], acc[i][j], 0, 0, 0);
        }
        __syncthreads();
    }

    const int q  = lane >> 4;
    const int lm = lane & 15;
#pragma unroll
    for (int i = 0; i < 4; ++i) {
        const int row = m0 + wm * 64 + i * 16 + q * 4;
#pragma unroll
        for (int j = 0; j < 4; ++j) {
            const int col = n0 + wn * 64 + j * 16 + lm;
            float* cp = C + (size_t)row * N + col;
#pragma unroll
            for (int r = 0; r < 4; ++r)
                cp[(size_t)r * N] = acc[i][j][r];
        }
    }
}

// ------------- LayerNorm over 3072 + gates, IN PLACE on buf ----------------
// after this kernel, row layout: [0..1023]=a=(1-g), [1024..2047]=b=g*x,
// [2048..3071]=hg=sigmoid(y)
__global__ __launch_bounds__(256) void ln_gates(float* __restrict__ buf,
                                                const float* __restrict__ gamma,
                                                const float* __restrict__ beta) {
    __shared__ float ly[N3];
    __shared__ float red[8];
    const int tid = threadIdx.x;
    float* p = buf + (size_t)blockIdx.x * N3;
    float v[12];
    float s = 0.f, ss = 0.f;
#pragma unroll
    for (int i = 0; i < 12; ++i) {
        v[i] = p[tid + i * 256];
        s  += v[i];
        ss += v[i] * v[i];
    }
#pragma unroll
    for (int off = 1; off < 64; off <<= 1) {
        s  += __shfl_xor(s, off);
        ss += __shfl_xor(ss, off);
    }
    if ((tid & 63) == 0) { red[tid >> 6] = s; red[4 + (tid >> 6)] = ss; }
    __syncthreads();
    s  = red[0] + red[1] + red[2] + red[3];
    ss = red[4] + red[5] + red[6] + red[7];
    const float mu  = s * (1.0f / 3072.0f);
    const float var = ss * (1.0f / 3072.0f) - mu * mu;
    const float rs  = rsqrtf(var + 1e-5f);
#pragma unroll
    for (int i = 0; i < 12; ++i) {
        const int c = tid + i * 256;
        ly[c] = (v[i] - mu) * rs * gamma[c] + beta[c];
    }
    __syncthreads();
#pragma unroll
    for (int i = 0; i < 4; ++i) {
        const int c = tid + i * 256;
        const float g  = sigmoidf(ly[c]);
        const float x  = ly[c + 1024];
        const float hg = sigmoidf(ly[c + 2048]);
        p[c]        = 1.0f - g;
        p[c + 1024] = g * x;
        p[c + 2048] = hg;
    }
}

// ---------------- segmented linear-recurrence scan -------------------------
// grid: (2, SEG, 32): x = channel chunk, y = segment, z = dir*16 + batch
__global__ __launch_bounds__(256) void scan_seg(const float* __restrict__ buf,
                                                float* __restrict__ segA,
                                                float* __restrict__ segB) {
    const int c   = blockIdx.x * 256 + threadIdx.x; // 0..511
    const int s   = blockIdx.y;
    const int dir = blockIdx.z >> 4;
    const int b   = blockIdx.z & 15;
    const int cg  = dir * HALF + c;
    const size_t base = (size_t)b * N3 + cg;
    float Aacc = 1.0f, Bacc = 0.0f;
    if (dir == 0) {
#pragma unroll 4
        for (int i = 0; i < SEGLEN; ++i) {
            const size_t idx = (size_t)(s * SEGLEN + i) * (B_DIM * N3) + base;
            const float a  = buf[idx];
            const float bv = buf[idx + 1024];
            Aacc *= a;
            Bacc = a * Bacc + bv;
        }
    } else {
#pragma unroll 4
        for (int i = SEGLEN - 1; i >= 0; --i) {
            const size_t idx = (size_t)(s * SEGLEN + i) * (B_DIM * N3) + base;
            const float a  = buf[idx];
            const float bv = buf[idx + 1024];
            Aacc *= a;
            Bacc = a * Bacc + bv;
        }
    }
    const int seq = (dir * 16 + b) * HALF + c;
    segA[s * NSEQ + seq] = Aacc;
    segB[s * NSEQ + seq] = Bacc;
}

// exclusive carry scan across segments; segB[s] becomes initial h for segment s.
// Forward sequences (seq < 8192): carry flows s = 0 -> 31.
// Backward sequences (seq >= 8192): h_t = a_t*h_{t+1} + b_t, so segment s's
// incoming state comes from segment s+1 -> carry flows s = 31 -> 0.
__global__ __launch_bounds__(256) void scan_carry(const float* __restrict__ segA,
                                                  float* __restrict__ segB) {
    const int seq = blockIdx.x * 256 + threadIdx.x;
    const int dir = seq >> 13;   // 8192 boundary, block-aligned -> uniform
    float h = 0.f;
    if (dir == 0) {
        for (int s = 0; s < SEG; ++s) {
            const float Av = segA[s * NSEQ + seq];
            const float Bv = segB[s * NSEQ + seq];
            segB[s * NSEQ + seq] = h;
            h = Av * h + Bv;
        }
    } else {
        for (int s = SEG - 1; s >= 0; --s) {
            const float Av = segA[s * NSEQ + seq];
            const float Bv = segB[s * NSEQ + seq];
            segB[s * NSEQ + seq] = h;
            h = Av * h + Bv;
        }
    }
}

// apply scan within segment, fused with output combine
__global__ __launch_bounds__(256) void scan_apply(const float* __restrict__ buf,
                                                  const float* __restrict__ segB,
                                                  const float* __restrict__ input,
                                                  float* __restrict__ out) {
    const int c   = blockIdx.x * 256 + threadIdx.x;
    const int s   = blockIdx.y;
    const int dir = blockIdx.z >> 4;
    const int b   = blockIdx.z & 15;
    const int cg  = dir * HALF + c;
    const int seq = (dir * 16 + b) * HALF + c;
    float h = segB[s * NSEQ + seq];
    const size_t base3 = (size_t)b * N3 + cg;
    const size_t base1 = (size_t)b * D_DIM + cg;
    if (dir == 0) {
#pragma unroll 4
        for (int i = 0; i < SEGLEN; ++i) {
            const int t = s * SEGLEN + i;
            const size_t i3 = (size_t)t * (B_DIM * N3) + base3;
            const size_t i1 = (size_t)t * (B_DIM * D_DIM) + base1;
            const float a  = buf[i3];
            const float bv = buf[i3 + 1024];
            const float hg = buf[i3 + 2048];
            h = a * h + bv;
            out[i1] = (1.0f - hg) * h + input[i1] * hg;
        }
    } else {
#pragma unroll 4
        for (int i = SEGLEN - 1; i >= 0; --i) {
            const int t = s * SEGLEN + i;
            const size_t i3 = (size_t)t * (B_DIM * N3) + base3;
            const size_t i1 = (size_t)t * (B_DIM * D_DIM) + base1;
            const float a  = buf[i3];
            const float bv = buf[i3 + 1024];
            const float hg = buf[i3 + 2048];
            h = a * h + bv;
            out[i1] = (1.0f - hg) * h + input[i1] * hg;
        }
    }
}

extern "C" void kernel_launch(void* const* d_in, const int* in_sizes, int n_in,
                              void* d_out, int out_size, void* d_ws, size_t ws_size,
                              hipStream_t stream) {
    const float* input = (const float*)d_in[0];  // (T,B,D)
    const float* W     = (const float*)d_in[1];  // (D, 3D)
    const float* gamma = (const float*)d_in[2];  // (3D,)
    const float* beta  = (const float*)d_in[3];  // (3D,)
    float* out = (float*)d_out;                  // (T,B,D)

    char* ws = (char*)d_ws;
    const size_t szA   = (size_t)M_ROWS * D_DIM * 2;  // 64 MB bf16 A
    const size_t szWT  = (size_t)N3 * D_DIM * 2;      // 6 MB bf16 W^T
    const size_t szBuf = (size_t)M_ROWS * N3 * 4;     // 384 MB pre/gates
    ushort* Abf  = (ushort*)ws;
    ushort* WT   = (ushort*)(ws + szA);
    float*  buf  = (float*)(ws + szA + szWT);
    float*  segA = (float*)(ws + szA + szWT + szBuf);
    float*  segB = segA + (size_t)SEG * NSEQ;

    cast_a<<<(M_ROWS * D_DIM) / (256 * 8), 256, 0, stream>>>(input, Abf);
    transpose_cast<<<dim3(N3 / 64, D_DIM / 64), 256, 0, stream>>>(W, WT);
    gemm_bf16<<<dim3(M_ROWS / 128, N3 / 128), 256, 0, stream>>>(Abf, WT, buf);
    ln_gates<<<M_ROWS, 256, 0, stream>>>(buf, gamma, beta);
    scan_seg<<<dim3(2, SEG, 32), 256, 0, stream>>>(buf, segA, segB);
    scan_carry<<<NSEQ / 256, 256, 0, stream>>>(segA, segB);
    scan_apply<<<dim3(2, SEG, 32), 256, 0, stream>>>(buf, segB, input, out);
}

// Round 3
// 913.101 us; speedup vs baseline: 1.0035x; 1.0035x over previous
//
#include <hip/hip_runtime.h>
#include <hip/hip_bf16.h>
#include <cstdint>

#define T_DIM 2048
#define B_DIM 16
#define D_DIM 1024
#define N3    (3*D_DIM)          // 3072
#define M_ROWS (T_DIM*B_DIM)     // 32768
#define HALF  (D_DIM/2)          // 512
#define SEG    32
#define SEGLEN (T_DIM/SEG)       // 64
#define NSEQ  (2*B_DIM*HALF)     // 16384

typedef __attribute__((ext_vector_type(8))) short bf16x8;
typedef __attribute__((ext_vector_type(4))) float f32x4;

#define GLD_LDS16(g, l) __builtin_amdgcn_global_load_lds( \
    (const __attribute__((address_space(1))) void*)(g),   \
    (__attribute__((address_space(3))) void*)(l), 16, 0, 0)

__device__ __forceinline__ ushort f2bf(float x) {
    __hip_bfloat16 h = __float2bfloat16(x);
    return *reinterpret_cast<ushort*>(&h);
}

__device__ __forceinline__ float sigmoidf(float x) {
    return 1.0f / (1.0f + __expf(-x));
}

// ---------------- cast input (fp32 -> bf16), 8 elems/thread ----------------
__global__ __launch_bounds__(256) void cast_a(const float* __restrict__ in,
                                              ushort* __restrict__ out) {
    const size_t i = (size_t)blockIdx.x * 256 + threadIdx.x; // handles 8 elems
    const float4* p = (const float4*)in + i * 2;
    float4 a = p[0], b = p[1];
    float f[8] = {a.x, a.y, a.z, a.w, b.x, b.y, b.z, b.w};
    ushort r[8];
#pragma unroll
    for (int j = 0; j < 8; ++j) r[j] = f2bf(f[j]);
    *(uint4*)(out + i * 8) = *(const uint4*)r;
}

// ---------------- W (1024 x 3072) -> W^T (3072 x 1024) bf16 ----------------
__global__ __launch_bounds__(256) void transpose_cast(const float* __restrict__ W,
                                                      ushort* __restrict__ WT) {
    __shared__ float tile[64][65];
    const int c0 = blockIdx.x * 64;  // N dim of W
    const int r0 = blockIdx.y * 64;  // K dim of W
    const int tr = threadIdx.x >> 6; // 0..3
    const int tc = threadIdx.x & 63;
#pragma unroll
    for (int i = 0; i < 16; ++i) {
        const int r = tr + i * 4;
        tile[r][tc] = W[(size_t)(r0 + r) * N3 + c0 + tc];
    }
    __syncthreads();
#pragma unroll
    for (int i = 0; i < 16; ++i) {
        const int r = tr + i * 4;  // row of WT = col of W
        WT[(size_t)(c0 + r) * D_DIM + r0 + tc] = f2bf(tile[tc][r]);
    }
}

// ---------------- GEMM: C(32768x3072) = A(32768x1024) * B, BT is N x K -----
// LDS layout XOR-swizzled: LDS[row][chunk c] = global[row][c ^ (row&7)],
// chunks are 16B (8 bf16). Staging keeps wave-uniform base + lane*16 dest
// (global_load_lds constraint); the swizzle is applied on the GLOBAL chunk a
// lane fetches (still inside the same 128B row -> coalescing preserved).
// Fragment reads then hit 8 distinct bank groups over 8 rows -> 2-way
// aliasing only (free per m136), vs 16-way with the linear layout.
__global__ __launch_bounds__(256) void gemm_bf16(const ushort* __restrict__ A,
                                                 const ushort* __restrict__ BT,
                                                 float* __restrict__ C) {
    const int K = D_DIM;
    const int N = N3;
    __shared__ ushort As[128 * 64];
    __shared__ ushort Bs[128 * 64];
    const int tid  = threadIdx.x;
    const int wave = tid >> 6;
    const int lane = tid & 63;
    const int m0 = blockIdx.x * 128;
    const int n0 = blockIdx.y * 128;
    const int wm = wave >> 1;
    const int wn = wave & 1;

    f32x4 acc[4][4] = {};

    const int srow = lane >> 3;                         // row within 8-row group
    const int skc  = (((lane & 7) ^ (srow & 7)) * 8);   // swizzled k-chunk (elems)

    for (int k0 = 0; k0 < K; k0 += 64) {
#pragma unroll
        for (int it = 0; it < 4; ++it) {
            const int rb = it * 32 + wave * 8;
            GLD_LDS16(A  + (size_t)(m0 + rb + srow) * K + k0 + skc, &As[rb * 64]);
            GLD_LDS16(BT + (size_t)(n0 + rb + srow) * K + k0 + skc, &Bs[rb * 64]);
        }
        __syncthreads();
        const int q  = lane >> 4;
        const int lm = lane & 15;
        const int sw = lm & 7;                          // == row&7 for all frags
#pragma unroll
        for (int kk = 0; kk < 2; ++kk) {
            const int ch = ((kk * 4 + q) ^ sw) * 8;     // swizzled chunk offset
            bf16x8 af[4], bfr[4];
#pragma unroll
            for (int i = 0; i < 4; ++i) {
                af[i]  = *(const bf16x8*)&As[(wm * 64 + i * 16 + lm) * 64 + ch];
                bfr[i] = *(const bf16x8*)&Bs[(wn * 64 + i * 16 + lm) * 64 + ch];
            }
#pragma unroll
            for (int i = 0; i < 4; ++i)
#pragma unroll
                for (int j = 0; j < 4; ++j)
                    acc[i][j] = __builtin_amdgcn_mfma_f32_16x16x32_bf16(af[i], bfr[j], acc[i][j], 0, 0, 0);
        }
        __syncthreads();
    }

    const int q  = lane >> 4;
    const int lm = lane & 15;
#pragma unroll
    for (int i = 0; i < 4; ++i) {
        const int row = m0 + wm * 64 + i * 16 + q * 4;
#pragma unroll
        for (int j = 0; j < 4; ++j) {
            const int col = n0 + wn * 64 + j * 16 + lm;
            float* cp = C + (size_t)row * N + col;
#pragma unroll
            for (int r = 0; r < 4; ++r)
                cp[(size_t)r * N] = acc[i][j][r];
        }
    }
}

// ------------- LayerNorm over 3072 + gates, IN PLACE on buf ----------------
// after this kernel, row layout: [0..1023]=a=(1-g), [1024..2047]=b=g*x,
// [2048..3071]=hg=sigmoid(y)
__global__ __launch_bounds__(256) void ln_gates(float* __restrict__ buf,
                                                const float* __restrict__ gamma,
                                                const float* __restrict__ beta) {
    __shared__ float ly[N3];
    __shared__ float red[8];
    const int tid = threadIdx.x;
    float* p = buf + (size_t)blockIdx.x * N3;
    float v[12];
    float s = 0.f, ss = 0.f;
#pragma unroll
    for (int i = 0; i < 12; ++i) {
        v[i] = p[tid + i * 256];
        s  += v[i];
        ss += v[i] * v[i];
    }
#pragma unroll
    for (int off = 1; off < 64; off <<= 1) {
        s  += __shfl_xor(s, off);
        ss += __shfl_xor(ss, off);
    }
    if ((tid & 63) == 0) { red[tid >> 6] = s; red[4 + (tid >> 6)] = ss; }
    __syncthreads();
    s  = red[0] + red[1] + red[2] + red[3];
    ss = red[4] + red[5] + red[6] + red[7];
    const float mu  = s * (1.0f / 3072.0f);
    const float var = ss * (1.0f / 3072.0f) - mu * mu;
    const float rs  = rsqrtf(var + 1e-5f);
#pragma unroll
    for (int i = 0; i < 12; ++i) {
        const int c = tid + i * 256;
        ly[c] = (v[i] - mu) * rs * gamma[c] + beta[c];
    }
    __syncthreads();
#pragma unroll
    for (int i = 0; i < 4; ++i) {
        const int c = tid + i * 256;
        const float g  = sigmoidf(ly[c]);
        const float x  = ly[c + 1024];
        const float hg = sigmoidf(ly[c + 2048]);
        p[c]        = 1.0f - g;
        p[c + 1024] = g * x;
        p[c + 2048] = hg;
    }
}

// ---------------- segmented linear-recurrence scan -------------------------
// grid: (2, SEG, 32): x = channel chunk, y = segment, z = dir*16 + batch
__global__ __launch_bounds__(256) void scan_seg(const float* __restrict__ buf,
                                                float* __restrict__ segA,
                                                float* __restrict__ segB) {
    const int c   = blockIdx.x * 256 + threadIdx.x; // 0..511
    const int s   = blockIdx.y;
    const int dir = blockIdx.z >> 4;
    const int b   = blockIdx.z & 15;
    const int cg  = dir * HALF + c;
    const size_t base = (size_t)b * N3 + cg;
    float Aacc = 1.0f, Bacc = 0.0f;
    if (dir == 0) {
#pragma unroll 4
        for (int i = 0; i < SEGLEN; ++i) {
            const size_t idx = (size_t)(s * SEGLEN + i) * (B_DIM * N3) + base;
            const float a  = buf[idx];
            const float bv = buf[idx + 1024];
            Aacc *= a;
            Bacc = a * Bacc + bv;
        }
    } else {
#pragma unroll 4
        for (int i = SEGLEN - 1; i >= 0; --i) {
            const size_t idx = (size_t)(s * SEGLEN + i) * (B_DIM * N3) + base;
            const float a  = buf[idx];
            const float bv = buf[idx + 1024];
            Aacc *= a;
            Bacc = a * Bacc + bv;
        }
    }
    const int seq = (dir * 16 + b) * HALF + c;
    segA[s * NSEQ + seq] = Aacc;
    segB[s * NSEQ + seq] = Bacc;
}

// exclusive carry scan across segments; segB[s] becomes initial h for segment s.
// Forward sequences (seq < 8192): carry flows s = 0 -> 31.
// Backward sequences (seq >= 8192): h_t = a_t*h_{t+1} + b_t, so segment s's
// incoming state comes from segment s+1 -> carry flows s = 31 -> 0.
__global__ __launch_bounds__(256) void scan_carry(const float* __restrict__ segA,
                                                  float* __restrict__ segB) {
    const int seq = blockIdx.x * 256 + threadIdx.x;
    const int dir = seq >> 13;   // 8192 boundary, block-aligned -> uniform
    float h = 0.f;
    if (dir == 0) {
        for (int s = 0; s < SEG; ++s) {
            const float Av = segA[s * NSEQ + seq];
            const float Bv = segB[s * NSEQ + seq];
            segB[s * NSEQ + seq] = h;
            h = Av * h + Bv;
        }
    } else {
        for (int s = SEG - 1; s >= 0; --s) {
            const float Av = segA[s * NSEQ + seq];
            const float Bv = segB[s * NSEQ + seq];
            segB[s * NSEQ + seq] = h;
            h = Av * h + Bv;
        }
    }
}

// apply scan within segment, fused with output combine
__global__ __launch_bounds__(256) void scan_apply(const float* __restrict__ buf,
                                                  const float* __restrict__ segB,
                                                  const float* __restrict__ input,
                                                  float* __restrict__ out) {
    const int c   = blockIdx.x * 256 + threadIdx.x;
    const int s   = blockIdx.y;
    const int dir = blockIdx.z >> 4;
    const int b   = blockIdx.z & 15;
    const int cg  = dir * HALF + c;
    const int seq = (dir * 16 + b) * HALF + c;
    float h = segB[s * NSEQ + seq];
    const size_t base3 = (size_t)b * N3 + cg;
    const size_t base1 = (size_t)b * D_DIM + cg;
    if (dir == 0) {
#pragma unroll 4
        for (int i = 0; i < SEGLEN; ++i) {
            const int t = s * SEGLEN + i;
            const size_t i3 = (size_t)t * (B_DIM * N3) + base3;
            const size_t i1 = (size_t)t * (B_DIM * D_DIM) + base1;
            const float a  = buf[i3];
            const float bv = buf[i3 + 1024];
            const float hg = buf[i3 + 2048];
            h = a * h + bv;
            out[i1] = (1.0f - hg) * h + input[i1] * hg;
        }
    } else {
#pragma unroll 4
        for (int i = SEGLEN - 1; i >= 0; --i) {
            const int t = s * SEGLEN + i;
            const size_t i3 = (size_t)t * (B_DIM * N3) + base3;
            const size_t i1 = (size_t)t * (B_DIM * D_DIM) + base1;
            const float a  = buf[i3];
            const float bv = buf[i3 + 1024];
            const float hg = buf[i3 + 2048];
            h = a * h + bv;
            out[i1] = (1.0f - hg) * h + input[i1] * hg;
        }
    }
}

extern "C" void kernel_launch(void* const* d_in, const int* in_sizes, int n_in,
                              void* d_out, int out_size, void* d_ws, size_t ws_size,
                              hipStream_t stream) {
    const float* input = (const float*)d_in[0];  // (T,B,D)
    const float* W     = (const float*)d_in[1];  // (D, 3D)
    const float* gamma = (const float*)d_in[2];  // (3D,)
    const float* beta  = (const float*)d_in[3];  // (3D,)
    float* out = (float*)d_out;                  // (T,B,D)

    char* ws = (char*)d_ws;
    const size_t szA   = (size_t)M_ROWS * D_DIM * 2;  // 64 MB bf16 A
    const size_t szWT  = (size_t)N3 * D_DIM * 2;      // 6 MB bf16 W^T
    const size_t szBuf = (size_t)M_ROWS * N3 * 4;     // 384 MB pre/gates
    ushort* Abf  = (ushort*)ws;
    ushort* WT   = (ushort*)(ws + szA);
    float*  buf  = (float*)(ws + szA + szWT);
    float*  segA = (float*)(ws + szA + szWT + szBuf);
    float*  segB = segA + (size_t)SEG * NSEQ;

    cast_a<<<(M_ROWS * D_DIM) / (256 * 8), 256, 0, stream>>>(input, Abf);
    transpose_cast<<<dim3(N3 / 64, D_DIM / 64), 256, 0, stream>>>(W, WT);
    gemm_bf16<<<dim3(M_ROWS / 128, N3 / 128), 256, 0, stream>>>(Abf, WT, buf);
    ln_gates<<<M_ROWS, 256, 0, stream>>>(buf, gamma, beta);
    scan_seg<<<dim3(2, SEG, 32), 256, 0, stream>>>(buf, segA, segB);
    scan_carry<<<NSEQ / 256, 256, 0, stream>>>(segA, segB);
    scan_apply<<<dim3(2, SEG, 32), 256, 0, stream>>>(buf, segB, input, out);
}